// Round 11
// baseline (291.990 us; speedup 1.0000x reference)
//
#include <hip/hip_runtime.h>

#define S_LEN 8192
#define HID   1024
#define NHEAD 16
#define DH    64
#define WIN   128
#define NCHUNK (S_LEN / WIN)   // 64
#define NC2    (NCHUNK / 2)    // 32 chunk-pairs

typedef _Float16 half8   __attribute__((ext_vector_type(8)));
typedef _Float16 half4_t __attribute__((ext_vector_type(4)));
typedef float    f32x4   __attribute__((ext_vector_type(4)));

#define QPITCH 72    // sK row pitch in f16 elems (64 + 8 pad): read stride 144B ≡ 4 banks, ~2-way (free)
#define PPITCH 132   // sVt row pitch: write lane-stride 4*132*2=1056B ≡ 8 banks → 4-way (was 8-way at 136)

__global__ __launch_bounds__(512, 4)
void swa_fwd(const float* __restrict__ qg,
             const float* __restrict__ kg,
             const float* __restrict__ vg,
             float* __restrict__ og)
{
    const int c    = blockIdx.x;   // chunk-pair: query chunks 2c, 2c+1 (256 rows)
    const int h    = blockIdx.y;   // head
    const int b    = blockIdx.z;   // batch
    const int tid  = threadIdx.x;
    const int wave = tid >> 6;     // 0..7
    const int lane = tid & 63;
    const int l16  = lane & 15;
    const int quad = lane >> 4;
    const int hs   = wave >> 2;    // 0: queries [0,128), 1: [128,256)

    __shared__ _Float16 sK [128 * QPITCH];   // 18432 B
    __shared__ _Float16 sVt[ 64 * PPITCH];   // 16896 B  (V transposed: [dim][key])

    const size_t qbase  = (((size_t)b * S_LEN + (size_t)c * (2 * WIN)) * HID) + (size_t)h * DH;
    const size_t kvbase = (((size_t)b * S_LEN) * HID) + (size_t)h * DH;

    // ---- this wave's Q rows as B-fragments of S^T = K Q^T
    half8 qf[2][2];
    #pragma unroll
    for (int mt = 0; mt < 2; ++mt) {
        const int row = wave * 32 + mt * 16 + l16;    // block-local query 0..255
        const float* qrow = qg + qbase + (size_t)row * HID;
        #pragma unroll
        for (int kk = 0; kk < 2; ++kk) {
            const float4 a = *(const float4*)(qrow + kk * 32 + quad * 8);
            const float4 d = *(const float4*)(qrow + kk * 32 + quad * 8 + 4);
            qf[mt][kk] = (half8){ (_Float16)a.x, (_Float16)a.y, (_Float16)a.z, (_Float16)a.w,
                                  (_Float16)d.x, (_Float16)d.y, (_Float16)d.z, (_Float16)d.w };
        }
    }

    f32x4 Oacc[2][4];
    #pragma unroll
    for (int mt = 0; mt < 2; ++mt)
        #pragma unroll
        for (int dt = 0; dt < 4; ++dt) Oacc[mt][dt] = (f32x4){0.f, 0.f, 0.f, 0.f};
    float m_i[2] = { -3.0e38f, -3.0e38f };
    float l_i[2] = { 0.0f, 0.0f };

    // tiles t stage key chunk (2c - 1 + t); role = t - hs: 0=lower-mask, 1=full, 2=upper-mask
    const int t0 = (c == 0)       ? 1 : 0;
    const int t1 = (c == NC2 - 1) ? 2 : 3;
    const float L2E = 1.44269504088896f;

    for (int t = t0; t <= t1; ++t) {
        __syncthreads();   // all waves done reading sK/sVt from previous tile
        {
            const int r0 = tid >> 4;          // 0..31
            const int c4 = (tid & 15) * 4;
            const size_t kb = kvbase + (size_t)(c * (2 * WIN) + (t - 1) * WIN) * HID;
            #pragma unroll
            for (int p = 0; p < 4; ++p) {
                const int row = p * 32 + r0;
                const float4 f = *(const float4*)(kg + kb + (size_t)row * HID + c4);
                half4_t hk = { (_Float16)f.x, (_Float16)f.y, (_Float16)f.z, (_Float16)f.w };
                *(half4_t*)&sK[row * QPITCH + c4] = hk;
                const float4 g = *(const float4*)(vg + kb + (size_t)row * HID + c4);
                sVt[(c4 + 0) * PPITCH + row] = (_Float16)g.x;
                sVt[(c4 + 1) * PPITCH + row] = (_Float16)g.y;
                sVt[(c4 + 2) * PPITCH + row] = (_Float16)g.z;
                sVt[(c4 + 3) * PPITCH + row] = (_Float16)g.w;
            }
        }
        __syncthreads();

        const int role = t - hs;
        if (role < 0 || role > 2) continue;   // idle tile for this wave (barrier counts match)

        // ---- per-mt fused: QK^T -> softmax -> PV, with per-nt P->PV fusion (min live regs)
        #pragma unroll
        for (int mt = 0; mt < 2; ++mt) {
            // S^T = K Q^T : C tile [row=key nt*16+quad*4+r][col=query l16]
            f32x4 Sacc[8];
            #pragma unroll
            for (int nt = 0; nt < 8; ++nt) Sacc[nt] = (f32x4){0.f, 0.f, 0.f, 0.f};
            __builtin_amdgcn_s_setprio(1);
            #pragma unroll
            for (int kk = 0; kk < 2; ++kk) {
                #pragma unroll
                for (int nt = 0; nt < 8; ++nt) {
                    const half8 kf = *(const half8*)&sK[(nt * 16 + l16) * QPITCH + kk * 32 + quad * 8];
                    Sacc[nt] = __builtin_amdgcn_mfma_f32_16x16x32_f16(kf, qf[mt][kk], Sacc[nt], 0, 0, 0);
                }
            }
            __builtin_amdgcn_s_setprio(0);

            const int iq = (wave & 3) * 32 + mt * 16 + l16;   // query index within its chunk (0..127)
            if (role != 1) {
                #pragma unroll
                for (int nt = 0; nt < 8; ++nt) {
                    #pragma unroll
                    for (int r = 0; r < 4; ++r) {
                        const int j = nt * 16 + quad * 4 + r;   // local key index
                        const bool valid = (role == 0) ? (j >= iq) : (j <= iq);
                        if (!valid) Sacc[nt][r] = -3.0e38f;
                    }
                }
            }

            // online softmax max (tree; query = lane col)
            float mx = fmaxf(fmaxf(Sacc[0][0], Sacc[0][1]), fmaxf(Sacc[0][2], Sacc[0][3]));
            #pragma unroll
            for (int nt = 1; nt < 8; ++nt)
                mx = fmaxf(mx, fmaxf(fmaxf(Sacc[nt][0], Sacc[nt][1]),
                                     fmaxf(Sacc[nt][2], Sacc[nt][3])));
            mx = fmaxf(mx, __shfl_xor(mx, 16, 64));
            mx = fmaxf(mx, __shfl_xor(mx, 32, 64));
            const float mnew = fmaxf(m_i[mt], mx);
            const float alpha = exp2f((m_i[mt] - mnew) * L2E);
            m_i[mt] = mnew;

            // rescale O before accumulating this tile's PV
            #pragma unroll
            for (int dt = 0; dt < 4; ++dt) {
                Oacc[mt][dt][0] *= alpha; Oacc[mt][dt][1] *= alpha;
                Oacc[mt][dt][2] *= alpha; Oacc[mt][dt][3] *= alpha;
            }

            // fused P -> PV: per nt, compute 4 probs, convert, 4 MFMAs; Pf is 2 regs
            float rs = 0.0f;
            __builtin_amdgcn_s_setprio(1);
            #pragma unroll
            for (int nt = 0; nt < 8; ++nt) {
                const float p0 = exp2f((Sacc[nt][0] - mnew) * L2E);
                const float p1 = exp2f((Sacc[nt][1] - mnew) * L2E);
                const float p2 = exp2f((Sacc[nt][2] - mnew) * L2E);
                const float p3 = exp2f((Sacc[nt][3] - mnew) * L2E);
                rs += (p0 + p1) + (p2 + p3);
                const auto plo = __builtin_amdgcn_cvt_pkrtz(p0, p1);  // __fp16 x2
                const auto phi = __builtin_amdgcn_cvt_pkrtz(p2, p3);
                const half4_t pf = (half4_t){ (_Float16)plo.x, (_Float16)plo.y,
                                              (_Float16)phi.x, (_Float16)phi.y };
                #pragma unroll
                for (int dt = 0; dt < 4; ++dt) {
                    const half4_t vf = *(const half4_t*)&sVt[(dt * 16 + l16) * PPITCH + nt * 16 + quad * 4];
                    Oacc[mt][dt] = __builtin_amdgcn_mfma_f32_16x16x16f16(vf, pf, Oacc[mt][dt], 0, 0, 0);
                }
            }
            __builtin_amdgcn_s_setprio(0);

            rs += __shfl_xor(rs, 16, 64);
            rs += __shfl_xor(rs, 32, 64);
            l_i[mt] = l_i[mt] * alpha + rs;
        }
    }

    // ---- epilogue: O = (O^T)^T / l, float4 stores
    #pragma unroll
    for (int mt = 0; mt < 2; ++mt) {
        const float inv = 1.0f / l_i[mt];
        const int row = wave * 32 + mt * 16 + l16;          // block-local query row
        float* orow = og + qbase + (size_t)row * HID;
        #pragma unroll
        for (int dt = 0; dt < 4; ++dt) {
            float4 o = { Oacc[mt][dt][0] * inv, Oacc[mt][dt][1] * inv,
                         Oacc[mt][dt][2] * inv, Oacc[mt][dt][3] * inv };
            *(float4*)(orow + dt * 16 + quad * 4) = o;
        }
    }
}

extern "C" void kernel_launch(void* const* d_in, const int* in_sizes, int n_in,
                              void* d_out, int out_size, void* d_ws, size_t ws_size,
                              hipStream_t stream) {
    const float* q = (const float*)d_in[0];
    const float* k = (const float*)d_in[1];
    const float* v = (const float*)d_in[2];
    float* out = (float*)d_out;
    dim3 grid(NC2, NHEAD, 2);   // (chunk-pair, head, batch)
    dim3 block(512);
    swa_fwd<<<grid, block, 0, stream>>>(q, k, v, out);
}

// Round 12
// 284.580 us; speedup vs baseline: 1.0260x; 1.0260x over previous
//
#include <hip/hip_runtime.h>

#define S_LEN 8192
#define HID   1024
#define NHEAD 16
#define DH    64
#define WIN   128
#define NCHUNK (S_LEN / WIN)   // 64
#define NC2    (NCHUNK / 2)    // 32 chunk-pairs

typedef _Float16 half8   __attribute__((ext_vector_type(8)));
typedef _Float16 half4_t __attribute__((ext_vector_type(4)));
typedef float    f32x4   __attribute__((ext_vector_type(4)));

#define QPITCH 72    // sK row pitch in f16 elems (64 + 8 pad): read stride 144B ≡ 4 banks, ~2-way (free)
#define PPITCH 132   // sVt row pitch: write lane-stride 4*132*2=1056B ≡ 8 banks → 4-way

// (512,2): 256-reg/wave budget. At (512,4) the unified file split 64 arch + 64 AGPR
// (Sacc+Oacc fill AGPR side exactly); arch side overflowed -> ~100 MB scratch traffic
// (VGPR_Count pinned at 64 across three source variants). Trade 2 blocks/CU -> 1 to
// eliminate spills entirely.
__global__ __launch_bounds__(512, 2)
void swa_fwd(const float* __restrict__ qg,
             const float* __restrict__ kg,
             const float* __restrict__ vg,
             float* __restrict__ og)
{
    const int c    = blockIdx.x;   // chunk-pair: query chunks 2c, 2c+1 (256 rows)
    const int h    = blockIdx.y;   // head
    const int b    = blockIdx.z;   // batch
    const int tid  = threadIdx.x;
    const int wave = tid >> 6;     // 0..7
    const int lane = tid & 63;
    const int l16  = lane & 15;
    const int quad = lane >> 4;
    const int hs   = wave >> 2;    // 0: queries [0,128), 1: [128,256)

    __shared__ _Float16 sK [128 * QPITCH];   // 18432 B
    __shared__ _Float16 sVt[ 64 * PPITCH];   // 16896 B  (V transposed: [dim][key])

    const size_t qbase  = (((size_t)b * S_LEN + (size_t)c * (2 * WIN)) * HID) + (size_t)h * DH;
    const size_t kvbase = (((size_t)b * S_LEN) * HID) + (size_t)h * DH;

    // ---- this wave's Q rows as B-fragments of S^T = K Q^T
    half8 qf[2][2];
    #pragma unroll
    for (int mt = 0; mt < 2; ++mt) {
        const int row = wave * 32 + mt * 16 + l16;    // block-local query 0..255
        const float* qrow = qg + qbase + (size_t)row * HID;
        #pragma unroll
        for (int kk = 0; kk < 2; ++kk) {
            const float4 a = *(const float4*)(qrow + kk * 32 + quad * 8);
            const float4 d = *(const float4*)(qrow + kk * 32 + quad * 8 + 4);
            qf[mt][kk] = (half8){ (_Float16)a.x, (_Float16)a.y, (_Float16)a.z, (_Float16)a.w,
                                  (_Float16)d.x, (_Float16)d.y, (_Float16)d.z, (_Float16)d.w };
        }
    }

    f32x4 Oacc[2][4];
    #pragma unroll
    for (int mt = 0; mt < 2; ++mt)
        #pragma unroll
        for (int dt = 0; dt < 4; ++dt) Oacc[mt][dt] = (f32x4){0.f, 0.f, 0.f, 0.f};
    float m_i[2] = { -3.0e38f, -3.0e38f };
    float l_i[2] = { 0.0f, 0.0f };

    // tiles t stage key chunk (2c - 1 + t); role = t - hs: 0=lower-mask, 1=full, 2=upper-mask
    const int t0 = (c == 0)       ? 1 : 0;
    const int t1 = (c == NC2 - 1) ? 2 : 3;
    const float L2E = 1.44269504088896f;

    for (int t = t0; t <= t1; ++t) {
        __syncthreads();   // all waves done reading sK/sVt from previous tile
        {
            const int r0 = tid >> 4;          // 0..31
            const int c4 = (tid & 15) * 4;
            const size_t kb = kvbase + (size_t)(c * (2 * WIN) + (t - 1) * WIN) * HID;
            #pragma unroll
            for (int p = 0; p < 4; ++p) {
                const int row = p * 32 + r0;
                const float4 f = *(const float4*)(kg + kb + (size_t)row * HID + c4);
                half4_t hk = { (_Float16)f.x, (_Float16)f.y, (_Float16)f.z, (_Float16)f.w };
                *(half4_t*)&sK[row * QPITCH + c4] = hk;
                const float4 g = *(const float4*)(vg + kb + (size_t)row * HID + c4);
                sVt[(c4 + 0) * PPITCH + row] = (_Float16)g.x;
                sVt[(c4 + 1) * PPITCH + row] = (_Float16)g.y;
                sVt[(c4 + 2) * PPITCH + row] = (_Float16)g.z;
                sVt[(c4 + 3) * PPITCH + row] = (_Float16)g.w;
            }
        }
        __syncthreads();

        const int role = t - hs;
        if (role < 0 || role > 2) continue;   // idle tile for this wave (barrier counts match)

        // ---- per-mt fused: QK^T -> softmax -> PV, with per-nt P->PV fusion
        #pragma unroll
        for (int mt = 0; mt < 2; ++mt) {
            // S^T = K Q^T : C tile [row=key nt*16+quad*4+r][col=query l16]
            f32x4 Sacc[8];
            #pragma unroll
            for (int nt = 0; nt < 8; ++nt) Sacc[nt] = (f32x4){0.f, 0.f, 0.f, 0.f};
            __builtin_amdgcn_s_setprio(1);
            #pragma unroll
            for (int kk = 0; kk < 2; ++kk) {
                #pragma unroll
                for (int nt = 0; nt < 8; ++nt) {
                    const half8 kf = *(const half8*)&sK[(nt * 16 + l16) * QPITCH + kk * 32 + quad * 8];
                    Sacc[nt] = __builtin_amdgcn_mfma_f32_16x16x32_f16(kf, qf[mt][kk], Sacc[nt], 0, 0, 0);
                }
            }
            __builtin_amdgcn_s_setprio(0);

            const int iq = (wave & 3) * 32 + mt * 16 + l16;   // query index within its chunk (0..127)
            if (role != 1) {
                #pragma unroll
                for (int nt = 0; nt < 8; ++nt) {
                    #pragma unroll
                    for (int r = 0; r < 4; ++r) {
                        const int j = nt * 16 + quad * 4 + r;   // local key index
                        const bool valid = (role == 0) ? (j >= iq) : (j <= iq);
                        if (!valid) Sacc[nt][r] = -3.0e38f;
                    }
                }
            }

            // online softmax max (tree; query = lane col)
            float mx = fmaxf(fmaxf(Sacc[0][0], Sacc[0][1]), fmaxf(Sacc[0][2], Sacc[0][3]));
            #pragma unroll
            for (int nt = 1; nt < 8; ++nt)
                mx = fmaxf(mx, fmaxf(fmaxf(Sacc[nt][0], Sacc[nt][1]),
                                     fmaxf(Sacc[nt][2], Sacc[nt][3])));
            mx = fmaxf(mx, __shfl_xor(mx, 16, 64));
            mx = fmaxf(mx, __shfl_xor(mx, 32, 64));
            const float mnew = fmaxf(m_i[mt], mx);
            const float alpha = exp2f((m_i[mt] - mnew) * L2E);
            m_i[mt] = mnew;

            // rescale O before accumulating this tile's PV
            #pragma unroll
            for (int dt = 0; dt < 4; ++dt) {
                Oacc[mt][dt][0] *= alpha; Oacc[mt][dt][1] *= alpha;
                Oacc[mt][dt][2] *= alpha; Oacc[mt][dt][3] *= alpha;
            }

            // fused P -> PV: per nt, compute 4 probs, convert, 4 MFMAs
            float rs = 0.0f;
            __builtin_amdgcn_s_setprio(1);
            #pragma unroll
            for (int nt = 0; nt < 8; ++nt) {
                const float p0 = exp2f((Sacc[nt][0] - mnew) * L2E);
                const float p1 = exp2f((Sacc[nt][1] - mnew) * L2E);
                const float p2 = exp2f((Sacc[nt][2] - mnew) * L2E);
                const float p3 = exp2f((Sacc[nt][3] - mnew) * L2E);
                rs += (p0 + p1) + (p2 + p3);
                const auto plo = __builtin_amdgcn_cvt_pkrtz(p0, p1);  // __fp16 x2
                const auto phi = __builtin_amdgcn_cvt_pkrtz(p2, p3);
                const half4_t pf = (half4_t){ (_Float16)plo.x, (_Float16)plo.y,
                                              (_Float16)phi.x, (_Float16)phi.y };
                #pragma unroll
                for (int dt = 0; dt < 4; ++dt) {
                    const half4_t vf = *(const half4_t*)&sVt[(dt * 16 + l16) * PPITCH + nt * 16 + quad * 4];
                    Oacc[mt][dt] = __builtin_amdgcn_mfma_f32_16x16x16f16(vf, pf, Oacc[mt][dt], 0, 0, 0);
                }
            }
            __builtin_amdgcn_s_setprio(0);

            rs += __shfl_xor(rs, 16, 64);
            rs += __shfl_xor(rs, 32, 64);
            l_i[mt] = l_i[mt] * alpha + rs;
        }
    }

    // ---- epilogue: O = (O^T)^T / l, float4 stores
    #pragma unroll
    for (int mt = 0; mt < 2; ++mt) {
        const float inv = 1.0f / l_i[mt];
        const int row = wave * 32 + mt * 16 + l16;          // block-local query row
        float* orow = og + qbase + (size_t)row * HID;
        #pragma unroll
        for (int dt = 0; dt < 4; ++dt) {
            float4 o = { Oacc[mt][dt][0] * inv, Oacc[mt][dt][1] * inv,
                         Oacc[mt][dt][2] * inv, Oacc[mt][dt][3] * inv };
            *(float4*)(orow + dt * 16 + quad * 4) = o;
        }
    }
}

extern "C" void kernel_launch(void* const* d_in, const int* in_sizes, int n_in,
                              void* d_out, int out_size, void* d_ws, size_t ws_size,
                              hipStream_t stream) {
    const float* q = (const float*)d_in[0];
    const float* k = (const float*)d_in[1];
    const float* v = (const float*)d_in[2];
    float* out = (float*)d_out;
    dim3 grid(NC2, NHEAD, 2);   // (chunk-pair, head, batch)
    dim3 block(512);
    swa_fwd<<<grid, block, 0, stream>>>(q, k, v, out);
}

// Round 16
// 272.453 us; speedup vs baseline: 1.0717x; 1.0445x over previous
//
#include <hip/hip_runtime.h>

#define S_LEN 8192
#define HID   1024
#define NHEAD 16
#define DH    64
#define WIN   128
#define NCHUNK (S_LEN / WIN)   // 64
#define NC2    (NCHUNK / 2)    // 32 chunk-pairs

typedef _Float16 half8   __attribute__((ext_vector_type(8)));
typedef _Float16 half4_t __attribute__((ext_vector_type(4)));
typedef float    f32x4   __attribute__((ext_vector_type(4)));

#define QPITCH 72    // sK row pitch in f16 elems (64 + 8 pad): read stride 144B ≡ 4 banks, ~2-way (free)
#define PPITCH 132   // sVt row pitch: write lane-stride 4*132*2=1056B ≡ 8 banks → 4-way

// (512,2): 256-reg/wave budget -> no spills (R12: WRITE_SIZE == output exactly).
__global__ __launch_bounds__(512, 2)
void swa_fwd(const float* __restrict__ qg,
             const float* __restrict__ kg,
             const float* __restrict__ vg,
             float* __restrict__ og)
{
    const int c    = blockIdx.x;   // chunk-pair: query chunks 2c, 2c+1 (256 rows)
    const int h    = blockIdx.y;   // head
    const int b    = blockIdx.z;   // batch
    const int tid  = threadIdx.x;
    const int wave = tid >> 6;     // 0..7
    const int lane = tid & 63;
    const int l16  = lane & 15;
    const int quad = lane >> 4;
    const int hs   = wave >> 2;    // 0: queries [0,128), 1: [128,256)

    __shared__ _Float16 sK [128 * QPITCH];   // 18432 B
    __shared__ _Float16 sVt[ 64 * PPITCH];   // 16896 B  (V transposed: [dim][key])

    const size_t qbase  = (((size_t)b * S_LEN + (size_t)c * (2 * WIN)) * HID) + (size_t)h * DH;
    const size_t kvbase = (((size_t)b * S_LEN) * HID) + (size_t)h * DH;

    // ---- this wave's Q rows as B-fragments of S^T = K Q^T
    half8 qf[2][2];
    #pragma unroll
    for (int mt = 0; mt < 2; ++mt) {
        const int row = wave * 32 + mt * 16 + l16;    // block-local query 0..255
        const float* qrow = qg + qbase + (size_t)row * HID;
        #pragma unroll
        for (int kk = 0; kk < 2; ++kk) {
            const float4 a = *(const float4*)(qrow + kk * 32 + quad * 8);
            const float4 d = *(const float4*)(qrow + kk * 32 + quad * 8 + 4);
            qf[mt][kk] = (half8){ (_Float16)a.x, (_Float16)a.y, (_Float16)a.z, (_Float16)a.w,
                                  (_Float16)d.x, (_Float16)d.y, (_Float16)d.z, (_Float16)d.w };
        }
    }

    f32x4 Oacc[2][4];
    #pragma unroll
    for (int mt = 0; mt < 2; ++mt)
        #pragma unroll
        for (int dt = 0; dt < 4; ++dt) Oacc[mt][dt] = (f32x4){0.f, 0.f, 0.f, 0.f};
    float m_i[2] = { -3.0e38f, -3.0e38f };
    float l_i[2] = { 0.0f, 0.0f };

    // tiles t stage key chunk (2c - 1 + t); role = t - hs: 0=lower-mask, 1=full, 2=upper-mask
    const int t0 = (c == 0)       ? 1 : 0;
    const int t1 = (c == NC2 - 1) ? 2 : 3;
    const float L2E = 1.44269504088896f;

    // ---- T14 async staging: prefetch tile t+1 into regs during compute of tile t
    const int r0 = tid >> 4;          // 0..31
    const int c4 = (tid & 15) * 4;
    float4 kreg[4], vreg[4];          // 32 VGPRs, live across compute

    auto loadtile = [&](int t) {
        const size_t kb = kvbase + (size_t)(c * (2 * WIN) + (t - 1) * WIN) * HID;
        #pragma unroll
        for (int p = 0; p < 4; ++p) {
            const int row = p * 32 + r0;
            kreg[p] = *(const float4*)(kg + kb + (size_t)row * HID + c4);
            vreg[p] = *(const float4*)(vg + kb + (size_t)row * HID + c4);
        }
    };

    loadtile(t0);

    for (int t = t0; t <= t1; ++t) {
        __syncthreads();   // all waves done reading sK/sVt from previous tile
        // write staged regs -> LDS (vmcnt wait here lands after prev compute, ~free)
        #pragma unroll
        for (int p = 0; p < 4; ++p) {
            const int row = p * 32 + r0;
            const float4 f = kreg[p];
            half4_t hk = { (_Float16)f.x, (_Float16)f.y, (_Float16)f.z, (_Float16)f.w };
            *(half4_t*)&sK[row * QPITCH + c4] = hk;
            const float4 g = vreg[p];
            sVt[(c4 + 0) * PPITCH + row] = (_Float16)g.x;
            sVt[(c4 + 1) * PPITCH + row] = (_Float16)g.y;
            sVt[(c4 + 2) * PPITCH + row] = (_Float16)g.z;
            sVt[(c4 + 3) * PPITCH + row] = (_Float16)g.w;
        }
        __syncthreads();

        if (t < t1) loadtile(t + 1);   // issue next tile's loads; HBM latency hides under compute

        const int role = t - hs;
        if (role >= 0 && role <= 2) {
            // ---- per-mt fused: QK^T -> softmax -> PV
            #pragma unroll
            for (int mt = 0; mt < 2; ++mt) {
                // S^T = K Q^T : C tile [row=key nt*16+quad*4+r][col=query l16]
                f32x4 Sacc[8];
                #pragma unroll
                for (int nt = 0; nt < 8; ++nt) Sacc[nt] = (f32x4){0.f, 0.f, 0.f, 0.f};
                __builtin_amdgcn_s_setprio(1);
                #pragma unroll
                for (int kk = 0; kk < 2; ++kk) {
                    #pragma unroll
                    for (int nt = 0; nt < 8; ++nt) {
                        const half8 kf = *(const half8*)&sK[(nt * 16 + l16) * QPITCH + kk * 32 + quad * 8];
                        Sacc[nt] = __builtin_amdgcn_mfma_f32_16x16x32_f16(kf, qf[mt][kk], Sacc[nt], 0, 0, 0);
                    }
                }
                __builtin_amdgcn_s_setprio(0);

                const int iq = (wave & 3) * 32 + mt * 16 + l16;   // query index within its chunk
                if (role != 1) {
                    #pragma unroll
                    for (int nt = 0; nt < 8; ++nt) {
                        #pragma unroll
                        for (int r = 0; r < 4; ++r) {
                            const int j = nt * 16 + quad * 4 + r;   // local key index
                            const bool valid = (role == 0) ? (j >= iq) : (j <= iq);
                            if (!valid) Sacc[nt][r] = -3.0e38f;
                        }
                    }
                }

                // online softmax max (tree; query = lane col)
                float mx = fmaxf(fmaxf(Sacc[0][0], Sacc[0][1]), fmaxf(Sacc[0][2], Sacc[0][3]));
                #pragma unroll
                for (int nt = 1; nt < 8; ++nt)
                    mx = fmaxf(mx, fmaxf(fmaxf(Sacc[nt][0], Sacc[nt][1]),
                                         fmaxf(Sacc[nt][2], Sacc[nt][3])));
                mx = fmaxf(mx, __shfl_xor(mx, 16, 64));
                mx = fmaxf(mx, __shfl_xor(mx, 32, 64));
                const float mnew = fmaxf(m_i[mt], mx);
                const float alpha = exp2f((m_i[mt] - mnew) * L2E);
                m_i[mt] = mnew;

                // rescale O before accumulating this tile's PV
                #pragma unroll
                for (int dt = 0; dt < 4; ++dt) {
                    Oacc[mt][dt][0] *= alpha; Oacc[mt][dt][1] *= alpha;
                    Oacc[mt][dt][2] *= alpha; Oacc[mt][dt][3] *= alpha;
                }

                // fused P -> PV: per nt, compute 4 probs, convert, 4 MFMAs
                float rs = 0.0f;
                __builtin_amdgcn_s_setprio(1);
                #pragma unroll
                for (int nt = 0; nt < 8; ++nt) {
                    const float p0 = exp2f((Sacc[nt][0] - mnew) * L2E);
                    const float p1 = exp2f((Sacc[nt][1] - mnew) * L2E);
                    const float p2 = exp2f((Sacc[nt][2] - mnew) * L2E);
                    const float p3 = exp2f((Sacc[nt][3] - mnew) * L2E);
                    rs += (p0 + p1) + (p2 + p3);
                    const auto plo = __builtin_amdgcn_cvt_pkrtz(p0, p1);  // __fp16 x2
                    const auto phi = __builtin_amdgcn_cvt_pkrtz(p2, p3);
                    const half4_t pf = (half4_t){ (_Float16)plo.x, (_Float16)plo.y,
                                                  (_Float16)phi.x, (_Float16)phi.y };
                    #pragma unroll
                    for (int dt = 0; dt < 4; ++dt) {
                        const half4_t vf = *(const half4_t*)&sVt[(dt * 16 + l16) * PPITCH + nt * 16 + quad * 4];
                        Oacc[mt][dt] = __builtin_amdgcn_mfma_f32_16x16x16f16(vf, pf, Oacc[mt][dt], 0, 0, 0);
                    }
                }
                __builtin_amdgcn_s_setprio(0);

                rs += __shfl_xor(rs, 16, 64);
                rs += __shfl_xor(rs, 32, 64);
                l_i[mt] = l_i[mt] * alpha + rs;
            }
        }
    }

    // ---- epilogue: O = (O^T)^T / l, float4 stores
    #pragma unroll
    for (int mt = 0; mt < 2; ++mt) {
        const float inv = 1.0f / l_i[mt];
        const int row = wave * 32 + mt * 16 + l16;          // block-local query row
        float* orow = og + qbase + (size_t)row * HID;
        #pragma unroll
        for (int dt = 0; dt < 4; ++dt) {
            float4 o = { Oacc[mt][dt][0] * inv, Oacc[mt][dt][1] * inv,
                         Oacc[mt][dt][2] * inv, Oacc[mt][dt][3] * inv };
            *(float4*)(orow + dt * 16 + quad * 4) = o;
        }
    }
}

extern "C" void kernel_launch(void* const* d_in, const int* in_sizes, int n_in,
                              void* d_out, int out_size, void* d_ws, size_t ws_size,
                              hipStream_t stream) {
    const float* q = (const float*)d_in[0];
    const float* k = (const float*)d_in[1];
    const float* v = (const float*)d_in[2];
    float* out = (float*)d_out;
    dim3 grid(NC2, NHEAD, 2);   // (chunk-pair, head, batch)
    dim3 block(512);
    swa_fwd<<<grid, block, 0, stream>>>(q, k, v, out);
}

// Round 19
// 269.184 us; speedup vs baseline: 1.0847x; 1.0121x over previous
//
#include <hip/hip_runtime.h>

#define S_LEN 8192
#define HID   1024
#define NHEAD 16
#define DH    64
#define WIN   128
#define NCHUNK (S_LEN / WIN)   // 64
#define NC2    (NCHUNK / 2)    // 32 chunk-pairs

typedef _Float16 half8   __attribute__((ext_vector_type(8)));
typedef _Float16 half4_t __attribute__((ext_vector_type(4)));
typedef float    f32x4   __attribute__((ext_vector_type(4)));

#define QPITCH 72    // sK row pitch in f16 elems (64 + 8 pad): read stride 144B ≡ 4 banks, ~2-way (free)
#define PPITCH 132   // sVt row pitch: write lane-stride 4*132*2=1056B ≡ 8 banks → 4-way

// (512,2): 256-reg/wave budget -> no spills (R12: WRITE_SIZE == output exactly).
__global__ __launch_bounds__(512, 2)
void swa_fwd(const float* __restrict__ qg,
             const float* __restrict__ kg,
             const float* __restrict__ vg,
             float* __restrict__ og)
{
    const int c    = blockIdx.x;   // chunk-pair: query chunks 2c, 2c+1 (256 rows)
    const int h    = blockIdx.y;   // head
    const int b    = blockIdx.z;   // batch
    const int tid  = threadIdx.x;
    const int wave = tid >> 6;     // 0..7
    const int lane = tid & 63;
    const int l16  = lane & 15;
    const int quad = lane >> 4;
    const int hs   = wave >> 2;    // 0: queries [0,128), 1: [128,256)
    const int w    = wave & 3;

    __shared__ _Float16 sK [128 * QPITCH];   // 18432 B
    __shared__ _Float16 sVt[ 64 * PPITCH];   // 16896 B  (V transposed: [dim][key])

    const size_t qbase  = (((size_t)b * S_LEN + (size_t)c * (2 * WIN)) * HID) + (size_t)h * DH;
    const size_t kvbase = (((size_t)b * S_LEN) * HID) + (size_t)h * DH;

    // ---- anti-diagonal row-tile pairing: wave w owns 16-row tiles {w, 7-w} of its chunk.
    // Balances the triangular mask skip: every wave does 9 blocks on role0/role2, 16 on role1.
    // ---- this wave's Q rows as B-fragments of S^T = K Q^T
    half8 qf[2][2];
    #pragma unroll
    for (int mt = 0; mt < 2; ++mt) {
        const int tidx = (mt == 0) ? w : (7 - w);
        const int row  = hs * 128 + tidx * 16 + l16;   // block-local query 0..255
        const float* qrow = qg + qbase + (size_t)row * HID;
        #pragma unroll
        for (int kk = 0; kk < 2; ++kk) {
            const float4 a = *(const float4*)(qrow + kk * 32 + quad * 8);
            const float4 d = *(const float4*)(qrow + kk * 32 + quad * 8 + 4);
            qf[mt][kk] = (half8){ (_Float16)a.x, (_Float16)a.y, (_Float16)a.z, (_Float16)a.w,
                                  (_Float16)d.x, (_Float16)d.y, (_Float16)d.z, (_Float16)d.w };
        }
    }

    f32x4 Oacc[2][4];
    #pragma unroll
    for (int mt = 0; mt < 2; ++mt)
        #pragma unroll
        for (int dt = 0; dt < 4; ++dt) Oacc[mt][dt] = (f32x4){0.f, 0.f, 0.f, 0.f};
    float m_i[2] = { -3.0e38f, -3.0e38f };
    float l_i[2] = { 0.0f, 0.0f };

    // tiles t stage key chunk (2c - 1 + t); role = t - hs: 0=lower-mask, 1=full, 2=upper-mask
    const int t0 = (c == 0)       ? 1 : 0;
    const int t1 = (c == NC2 - 1) ? 2 : 3;
    const float L2E = 1.44269504088896f;

    // ---- T14 async staging: prefetch tile t+1 into regs during compute of tile t
    const int r0 = tid >> 4;          // 0..31
    const int c4 = (tid & 15) * 4;
    float4 kreg[4], vreg[4];          // 32 VGPRs, live across compute

    auto loadtile = [&](int t) {
        const size_t kb = kvbase + (size_t)(c * (2 * WIN) + (t - 1) * WIN) * HID;
        #pragma unroll
        for (int p = 0; p < 4; ++p) {
            const int row = p * 32 + r0;
            kreg[p] = *(const float4*)(kg + kb + (size_t)row * HID + c4);
            vreg[p] = *(const float4*)(vg + kb + (size_t)row * HID + c4);
        }
    };

    loadtile(t0);

    for (int t = t0; t <= t1; ++t) {
        __syncthreads();   // all waves done reading sK/sVt from previous tile
        // write staged regs -> LDS (vmcnt wait here lands after prev compute, ~free)
        #pragma unroll
        for (int p = 0; p < 4; ++p) {
            const int row = p * 32 + r0;
            const float4 f = kreg[p];
            half4_t hk = { (_Float16)f.x, (_Float16)f.y, (_Float16)f.z, (_Float16)f.w };
            *(half4_t*)&sK[row * QPITCH + c4] = hk;
            const float4 g = vreg[p];
            sVt[(c4 + 0) * PPITCH + row] = (_Float16)g.x;
            sVt[(c4 + 1) * PPITCH + row] = (_Float16)g.y;
            sVt[(c4 + 2) * PPITCH + row] = (_Float16)g.z;
            sVt[(c4 + 3) * PPITCH + row] = (_Float16)g.w;
        }
        __syncthreads();

        if (t < t1) loadtile(t + 1);   // issue next tile's loads; HBM latency hides under compute

        const int role = t - hs;
        if (role >= 0 && role <= 2) {
            // ---- per-mt fused: QK^T -> softmax -> PV, with banded nt-block skip
            #pragma unroll
            for (int mt = 0; mt < 2; ++mt) {
                const int tidx = (mt == 0) ? w : (7 - w);
                const int lo   = (role == 0) ? tidx : 0;   // wave-uniform skip bounds
                const int hi   = (role == 2) ? tidx : 7;

                // S^T = K Q^T over in-band blocks only
                f32x4 Sacc[8];
                __builtin_amdgcn_s_setprio(1);
                #pragma unroll
                for (int nt = 0; nt < 8; ++nt) {
                    if (nt < lo || nt > hi) continue;
                    f32x4 acc = (f32x4){0.f, 0.f, 0.f, 0.f};
                    #pragma unroll
                    for (int kk = 0; kk < 2; ++kk) {
                        const half8 kf = *(const half8*)&sK[(nt * 16 + l16) * QPITCH + kk * 32 + quad * 8];
                        acc = __builtin_amdgcn_mfma_f32_16x16x32_f16(kf, qf[mt][kk], acc, 0, 0, 0);
                    }
                    // only the diagonal block needs the per-lane band mask
                    if (role != 1 && nt == tidx) {
                        #pragma unroll
                        for (int r = 0; r < 4; ++r) {
                            const int jj = quad * 4 + r;   // key index within block
                            const bool valid = (role == 0) ? (jj >= l16) : (jj <= l16);
                            if (!valid) acc[r] = -3.0e38f;
                        }
                    }
                    Sacc[nt] = acc;
                }
                __builtin_amdgcn_s_setprio(0);

                // online softmax max (query = lane col)
                float mx = -3.0e38f;
                #pragma unroll
                for (int nt = 0; nt < 8; ++nt) {
                    if (nt < lo || nt > hi) continue;
                    mx = fmaxf(mx, fmaxf(fmaxf(Sacc[nt][0], Sacc[nt][1]),
                                         fmaxf(Sacc[nt][2], Sacc[nt][3])));
                }
                mx = fmaxf(mx, __shfl_xor(mx, 16, 64));
                mx = fmaxf(mx, __shfl_xor(mx, 32, 64));
                const float mnew = fmaxf(m_i[mt], mx);
                const float alpha = exp2f((m_i[mt] - mnew) * L2E);
                m_i[mt] = mnew;

                // rescale O before accumulating this tile's PV
                #pragma unroll
                for (int dt = 0; dt < 4; ++dt) {
                    Oacc[mt][dt][0] *= alpha; Oacc[mt][dt][1] *= alpha;
                    Oacc[mt][dt][2] *= alpha; Oacc[mt][dt][3] *= alpha;
                }

                // fused P -> PV over in-band blocks
                float rs = 0.0f;
                __builtin_amdgcn_s_setprio(1);
                #pragma unroll
                for (int nt = 0; nt < 8; ++nt) {
                    if (nt < lo || nt > hi) continue;
                    const float p0 = exp2f((Sacc[nt][0] - mnew) * L2E);
                    const float p1 = exp2f((Sacc[nt][1] - mnew) * L2E);
                    const float p2 = exp2f((Sacc[nt][2] - mnew) * L2E);
                    const float p3 = exp2f((Sacc[nt][3] - mnew) * L2E);
                    rs += (p0 + p1) + (p2 + p3);
                    const auto plo = __builtin_amdgcn_cvt_pkrtz(p0, p1);  // __fp16 x2
                    const auto phi = __builtin_amdgcn_cvt_pkrtz(p2, p3);
                    const half4_t pf = (half4_t){ (_Float16)plo.x, (_Float16)plo.y,
                                                  (_Float16)phi.x, (_Float16)phi.y };
                    #pragma unroll
                    for (int dt = 0; dt < 4; ++dt) {
                        const half4_t vf = *(const half4_t*)&sVt[(dt * 16 + l16) * PPITCH + nt * 16 + quad * 4];
                        Oacc[mt][dt] = __builtin_amdgcn_mfma_f32_16x16x16f16(vf, pf, Oacc[mt][dt], 0, 0, 0);
                    }
                }
                __builtin_amdgcn_s_setprio(0);

                rs += __shfl_xor(rs, 16, 64);
                rs += __shfl_xor(rs, 32, 64);
                l_i[mt] = l_i[mt] * alpha + rs;
            }
        }
    }

    // ---- epilogue: O = (O^T)^T / l, float4 stores
    #pragma unroll
    for (int mt = 0; mt < 2; ++mt) {
        const float inv = 1.0f / l_i[mt];
        const int tidx = (mt == 0) ? w : (7 - w);
        const int row  = hs * 128 + tidx * 16 + l16;        // block-local query row
        float* orow = og + qbase + (size_t)row * HID;
        #pragma unroll
        for (int dt = 0; dt < 4; ++dt) {
            float4 o = { Oacc[mt][dt][0] * inv, Oacc[mt][dt][1] * inv,
                         Oacc[mt][dt][2] * inv, Oacc[mt][dt][3] * inv };
            *(float4*)(orow + dt * 16 + quad * 4) = o;
        }
    }
}

extern "C" void kernel_launch(void* const* d_in, const int* in_sizes, int n_in,
                              void* d_out, int out_size, void* d_ws, size_t ws_size,
                              hipStream_t stream) {
    const float* q = (const float*)d_in[0];
    const float* k = (const float*)d_in[1];
    const float* v = (const float*)d_in[2];
    float* out = (float*)d_out;
    dim3 grid(NC2, NHEAD, 2);   // (chunk-pair, head, batch)
    dim3 block(512);
    swa_fwd<<<grid, block, 0, stream>>>(q, k, v, out);
}